// Round 4
// baseline (778.113 us; speedup 1.0000x reference)
//
#include <hip/hip_runtime.h>
#include <hip/hip_bf16.h>

typedef __attribute__((ext_vector_type(8))) short bf16x8;
typedef __attribute__((ext_vector_type(4))) float f32x4;

__device__ __forceinline__ unsigned short f2bf(float f) {
    unsigned int u = __builtin_bit_cast(unsigned int, f);
    u += 0x7fffu + ((u >> 16) & 1u);   // round-to-nearest-even
    return (unsigned short)(u >> 16);
}

// Swizzled byte offset inside a [128 rows][256 B] LDS tile (16B-unit XOR).
__device__ __forceinline__ int swz(int r, int k /*bf16 col*/) {
    int unit = k >> 3;
    return r * 256 + (((unit ^ (r & 15)) << 4) | ((k & 7) << 1));
}

__global__ __launch_bounds__(256, 4)
void gemm_persist(const float* __restrict__ A,  // (32, 2048, 128)
                  const float* __restrict__ B,  // (32, 128, 2048)
                  float* __restrict__ C) {      // (32, 2048, 2048)
    // LDS: only the transposed B tile (128n x 128k bf16, swizzled) = 32 KB,
    // staged ONCE per block; the 4-tile mt-loop is barrier-free.
    __shared__ __align__(16) unsigned char lds[32768];

    // 2048 blocks = 128 outer (bh*4 + mtg) x 16 nt. XCD-chunked: XCD x owns
    // outer in [x*16, x*16+16) so its 16-nt siblings share A panels in L2.
    const int bid   = blockIdx.x;           // 0..2047
    const int xcd   = bid & 7;
    const int c     = bid >> 3;             // 0..255
    const int outer = xcd * 16 + (c >> 4);  // 0..127
    const int nt    = c & 15;
    const int bh    = outer >> 2;           // 0..31
    const int mtg   = outer & 3;            // 4-tile group

    const float* Bg  = B + (size_t)bh * (128 * 2048) + nt * 128;
    const float* Ag0 = A + (size_t)bh * (2048 * 128) + (size_t)mtg * (512 * 128);
    float*       Cg0 = C + (size_t)bh * (2048 * 2048) + (size_t)mtg * (512 * 2048) + nt * 128;

    const int t = threadIdx.x;

    // ---- stage B tile: 128(k) x 128(n) fp32, in-register 4x4 transpose
    //      -> bf16 LDS Bt[n][k], swizzled ----
#pragma unroll
    for (int s = 0; s < 4; ++s) {
        const int k0 = s * 32 + ((t >> 5) << 2);
        const int n0 = (t & 31) << 2;
        const float4 r0 = *(const float4*)(Bg + (size_t)(k0 + 0) * 2048 + n0);
        const float4 r1 = *(const float4*)(Bg + (size_t)(k0 + 1) * 2048 + n0);
        const float4 r2 = *(const float4*)(Bg + (size_t)(k0 + 2) * 2048 + n0);
        const float4 r3 = *(const float4*)(Bg + (size_t)(k0 + 3) * 2048 + n0);
        const float c0[4] = {r0.x, r0.y, r0.z, r0.w};
        const float c1[4] = {r1.x, r1.y, r1.z, r1.w};
        const float c2[4] = {r2.x, r2.y, r2.z, r2.w};
        const float c3[4] = {r3.x, r3.y, r3.z, r3.w};
#pragma unroll
        for (int j = 0; j < 4; ++j) {
            uint2 w;
            w.x = (unsigned int)f2bf(c0[j]) | ((unsigned int)f2bf(c1[j]) << 16);
            w.y = (unsigned int)f2bf(c2[j]) | ((unsigned int)f2bf(c3[j]) << 16);
            *(uint2*)(&lds[swz(n0 + j, k0)]) = w;
        }
    }

    __syncthreads();

    // ---- mt-loop: wave w owns rows [w*32, w*32+32) of each 128-row tile
    const int l  = t & 63;
    const int w  = t >> 6;
    const int wm = w * 32;
    const int lr = l & 15;          // fragment lane row
    const int lg = l >> 4;          // k-group (0..3)

    f32x4  raw[2][4][2];            // prefetched fp32 A fragments [mi][kk][half]
    bf16x8 abf[2][4];               // converted bf16 A fragments [mi][kk]

    // prefetch tile 0
#pragma unroll
    for (int mi = 0; mi < 2; ++mi) {
        const float* p = Ag0 + (size_t)(wm + mi * 16 + lr) * 128 + lg * 8;
#pragma unroll
        for (int kk = 0; kk < 4; ++kk) {
            raw[mi][kk][0] = *(const f32x4*)(p + kk * 32);
            raw[mi][kk][1] = *(const f32x4*)(p + kk * 32 + 4);
        }
    }

#pragma unroll 1
    for (int tt = 0; tt < 4; ++tt) {
        // convert prefetched raw -> bf16 fragments
#pragma unroll
        for (int mi = 0; mi < 2; ++mi)
#pragma unroll
            for (int kk = 0; kk < 4; ++kk) {
                bf16x8 v;
#pragma unroll
                for (int j = 0; j < 4; ++j) {
                    v[j]     = (short)f2bf(raw[mi][kk][0][j]);
                    v[4 + j] = (short)f2bf(raw[mi][kk][1][j]);
                }
                abf[mi][kk] = v;
            }

        // issue next tile's A loads BEFORE this tile's stores
        if (tt < 3) {
#pragma unroll
            for (int mi = 0; mi < 2; ++mi) {
                const float* p = Ag0 + (size_t)((tt + 1) * 128 + wm + mi * 16 + lr) * 128 + lg * 8;
#pragma unroll
                for (int kk = 0; kk < 4; ++kk) {
                    raw[mi][kk][0] = *(const f32x4*)(p + kk * 32);
                    raw[mi][kk][1] = *(const f32x4*)(p + kk * 32 + 4);
                }
            }
        }

        f32x4 acc[2][8] = {};
#pragma unroll
        for (int kk = 0; kk < 4; ++kk) {
            const int kbase = kk * 32 + lg * 8;
#pragma unroll
            for (int ni = 0; ni < 8; ++ni) {
                const bf16x8 b = *(const bf16x8*)(&lds[swz(ni * 16 + lr, kbase)]);
                // swapped operands: lane holds C[m = lr][n = ni*16 + lg*4 + j]
                acc[0][ni] = __builtin_amdgcn_mfma_f32_16x16x32_bf16(b, abf[0][kk], acc[0][ni], 0, 0, 0);
                acc[1][ni] = __builtin_amdgcn_mfma_f32_16x16x32_bf16(b, abf[1][kk], acc[1][ni], 0, 0, 0);
            }
        }

        // plain stores (NOT nontemporal): L2 merges the per-row 64B halves
        // from adjacent ni instructions into full 128B dirty lines.
        float* Cr = Cg0 + (size_t)(tt * 128) * 2048;
#pragma unroll
        for (int mi = 0; mi < 2; ++mi) {
            float* rowp = Cr + (size_t)(wm + mi * 16 + lr) * 2048 + lg * 4;
#pragma unroll
            for (int ni = 0; ni < 8; ++ni) {
                *(f32x4*)(rowp + ni * 16) = acc[mi][ni];
            }
        }
    }
}

extern "C" void kernel_launch(void* const* d_in, const int* in_sizes, int n_in,
                              void* d_out, int out_size, void* d_ws, size_t ws_size,
                              hipStream_t stream) {
    const float* x1 = (const float*)d_in[0];  // (2,16,2048,128)
    const float* x2 = (const float*)d_in[1];  // (2,16,128,2048)
    float* out = (float*)d_out;               // (2,16,2048,2048)
    gemm_persist<<<dim3(2048), dim3(256), 0, stream>>>(x1, x2, out);
}

// Round 5
// 260.426 us; speedup vs baseline: 2.9878x; 2.9878x over previous
//
#include <hip/hip_runtime.h>
#include <hip/hip_bf16.h>

typedef __attribute__((ext_vector_type(8))) short bf16x8;
typedef __attribute__((ext_vector_type(4))) float f32x4;

__device__ __forceinline__ unsigned short f2bf(float f) {
    unsigned int u = __builtin_bit_cast(unsigned int, f);
    u += 0x7fffu + ((u >> 16) & 1u);   // round-to-nearest-even
    return (unsigned short)(u >> 16);
}

// Swizzled byte offset inside the [128 rows][256 B] bf16 B tile (16B-unit XOR).
__device__ __forceinline__ int swz(int r, int k /*bf16 col*/) {
    int unit = k >> 3;
    return r * 256 + (((unit ^ (r & 15)) << 4) | ((k & 7) << 1));
}

// Swizzled byte offset inside a per-wave [16 rows][512 B] f32 C-stage tile.
// 16B units, unit' = unit ^ (row & 7): write (16 rows x same unit-low bits)
// and read (row-pair x all units) are both conflict-free.
__device__ __forceinline__ int swzC(int r, int u /*16B unit 0..31*/) {
    return r * 512 + ((u ^ (r & 7)) << 4);
}

#define C_STAGE_OFF 32768

__global__ __launch_bounds__(256, 2)
void gemm_persist(const float* __restrict__ A,  // (32, 2048, 128)
                  const float* __restrict__ B,  // (32, 128, 2048)
                  float* __restrict__ C) {      // (32, 2048, 2048)
    // LDS: 32 KB transposed B tile (staged once) + 4 x 8 KB per-wave C stage.
    __shared__ __align__(16) unsigned char lds[65536];

    // XCD-chunked mapping: XCD x gets bh in [x*4, x*4+4) -> 4 MB of A per L2.
    const int bid = blockIdx.x;                // 0..511
    const int c   = bid >> 3;                  // 0..63
    const int bh  = (bid & 7) * 4 + (c >> 4);  // 0..31
    const int nt  = c & 15;                    // 0..15

    const float* Bg  = B + (size_t)bh * (128 * 2048) + nt * 128;
    const float* Ag0 = A + (size_t)bh * (2048 * 128);
    float*       Cg0 = C + (size_t)bh * (2048 * 2048) + nt * 128;

    const int t = threadIdx.x;

    // ---- stage B tile: 128(k) x 128(n) fp32, in-register 4x4 transpose
    //      -> bf16 LDS Bt[n][k], swizzled ----
#pragma unroll
    for (int s = 0; s < 4; ++s) {
        const int k0 = s * 32 + ((t >> 5) << 2);
        const int n0 = (t & 31) << 2;
        const float4 r0 = *(const float4*)(Bg + (size_t)(k0 + 0) * 2048 + n0);
        const float4 r1 = *(const float4*)(Bg + (size_t)(k0 + 1) * 2048 + n0);
        const float4 r2 = *(const float4*)(Bg + (size_t)(k0 + 2) * 2048 + n0);
        const float4 r3 = *(const float4*)(Bg + (size_t)(k0 + 3) * 2048 + n0);
        const float c0[4] = {r0.x, r0.y, r0.z, r0.w};
        const float c1[4] = {r1.x, r1.y, r1.z, r1.w};
        const float c2[4] = {r2.x, r2.y, r2.z, r2.w};
        const float c3[4] = {r3.x, r3.y, r3.z, r3.w};
#pragma unroll
        for (int j = 0; j < 4; ++j) {
            uint2 w;
            w.x = (unsigned int)f2bf(c0[j]) | ((unsigned int)f2bf(c1[j]) << 16);
            w.y = (unsigned int)f2bf(c2[j]) | ((unsigned int)f2bf(c3[j]) << 16);
            *(uint2*)(&lds[swz(n0 + j, k0)]) = w;
        }
    }

    __syncthreads();

    // ---- persistent mt-loop: wave w owns rows [w*32, w*32+32) of each tile
    const int l  = t & 63;
    const int w  = t >> 6;
    const int wm = w * 32;
    const int lr = l & 15;          // fragment lane row
    const int lg = l >> 4;          // k-group (0..3)

    unsigned char* stg = &lds[C_STAGE_OFF + w * 8192];  // per-wave, no barrier

    f32x4  raw[2][4][2];            // prefetched fp32 A fragments [mi][kk][half]
    bf16x8 abf[2][4];               // converted bf16 A fragments [mi][kk]

    // prefetch mt = 0
#pragma unroll
    for (int mi = 0; mi < 2; ++mi) {
        const float* p = Ag0 + (size_t)(wm + mi * 16 + lr) * 128 + lg * 8;
#pragma unroll
        for (int kk = 0; kk < 4; ++kk) {
            raw[mi][kk][0] = *(const f32x4*)(p + kk * 32);
            raw[mi][kk][1] = *(const f32x4*)(p + kk * 32 + 4);
        }
    }

#pragma unroll 1
    for (int mt = 0; mt < 16; ++mt) {
        // convert prefetched raw -> bf16 fragments
#pragma unroll
        for (int mi = 0; mi < 2; ++mi)
#pragma unroll
            for (int kk = 0; kk < 4; ++kk) {
                bf16x8 v;
#pragma unroll
                for (int j = 0; j < 4; ++j) {
                    v[j]     = (short)f2bf(raw[mi][kk][0][j]);
                    v[4 + j] = (short)f2bf(raw[mi][kk][1][j]);
                }
                abf[mi][kk] = v;
            }

        // issue next tile's A loads BEFORE this tile's stores
        if (mt < 15) {
#pragma unroll
            for (int mi = 0; mi < 2; ++mi) {
                const float* p = Ag0 + (size_t)((mt + 1) * 128 + wm + mi * 16 + lr) * 128 + lg * 8;
#pragma unroll
                for (int kk = 0; kk < 4; ++kk) {
                    raw[mi][kk][0] = *(const f32x4*)(p + kk * 32);
                    raw[mi][kk][1] = *(const f32x4*)(p + kk * 32 + 4);
                }
            }
        }

        f32x4 acc[2][8] = {};
#pragma unroll
        for (int kk = 0; kk < 4; ++kk) {
            const int kbase = kk * 32 + lg * 8;
#pragma unroll
            for (int ni = 0; ni < 8; ++ni) {
                const bf16x8 b = *(const bf16x8*)(&lds[swz(ni * 16 + lr, kbase)]);
                // swapped operands: lane (lg,lr) holds C[m=lr][n=ni*16+lg*4+j]
                acc[0][ni] = __builtin_amdgcn_mfma_f32_16x16x32_bf16(b, abf[0][kk], acc[0][ni], 0, 0, 0);
                acc[1][ni] = __builtin_amdgcn_mfma_f32_16x16x32_bf16(b, abf[1][kk], acc[1][ni], 0, 0, 0);
            }
        }

        // ---- C write: round-trip through per-wave LDS stage so every
        // global store instruction covers FULL 128B lines (no partial-line
        // write amplification, no RFO). ----
        float* Cr = Cg0 + (size_t)(mt * 128) * 2048;
#pragma unroll
        for (int mi = 0; mi < 2; ++mi) {
            // scatter acc into stage: row lr, 16B unit ni*4+lg (swizzled)
#pragma unroll
            for (int ni = 0; ni < 8; ++ni)
                *(f32x4*)(stg + swzC(lr, ni * 4 + lg)) = acc[mi][ni];
            // gather dense: inst i covers rows 2i,2i+1; 32 lanes x 16B = one
            // contiguous 512B row segment each -> 4 full 128B lines per row
#pragma unroll
            for (int i = 0; i < 8; ++i) {
                const int r = 2 * i + (l >> 5);
                const f32x4 v = *(const f32x4*)(stg + swzC(r, l & 31));
                __builtin_nontemporal_store(
                    v, (f32x4*)(Cr + (size_t)(wm + mi * 16 + r) * 2048 + (l & 31) * 4));
            }
        }
    }
}

extern "C" void kernel_launch(void* const* d_in, const int* in_sizes, int n_in,
                              void* d_out, int out_size, void* d_ws, size_t ws_size,
                              hipStream_t stream) {
    const float* x1 = (const float*)d_in[0];  // (2,16,2048,128)
    const float* x2 = (const float*)d_in[1];  // (2,16,128,2048)
    float* out = (float*)d_out;               // (2,16,2048,2048)
    gemm_persist<<<dim3(512), dim3(256), 0, stream>>>(x1, x2, out);
}

// Round 6
// 177.689 us; speedup vs baseline: 4.3791x; 1.4656x over previous
//
#include <hip/hip_runtime.h>
#include <hip/hip_bf16.h>

typedef __attribute__((ext_vector_type(8)))  short bf16x8;
typedef __attribute__((ext_vector_type(4)))  float f32x4;
typedef __attribute__((ext_vector_type(16))) float f32x16;

__device__ __forceinline__ unsigned short f2bf(float f) {
    unsigned int u = __builtin_bit_cast(unsigned int, f);
    u += 0x7fffu + ((u >> 16) & 1u);   // round-to-nearest-even
    return (unsigned short)(u >> 16);
}

// Swizzled byte offset inside the [128 rows][256 B] bf16 B^T tile.
// 16B-unit XOR: unit' = unit ^ (row & 15). Any 8 consecutive rows at one
// unit map to 8 distinct units = 32 distinct banks -> conflict-free b128.
__device__ __forceinline__ int swz(int r, int k /*bf16 col*/) {
    int unit = k >> 3;
    return r * 256 + (((unit ^ (r & 15)) << 4) | ((k & 7) << 1));
}

__global__ __launch_bounds__(256, 2)
void gemm_persist(const float* __restrict__ A,  // (32, 2048, 128)
                  const float* __restrict__ B,  // (32, 128, 2048)
                  float* __restrict__ C) {      // (32, 2048, 2048)
    // LDS: only the transposed B tile (128n x 128k bf16, swizzled) = 32 KB,
    // staged ONCE per block; the 16-tile mt-loop is barrier-free.
    __shared__ __align__(16) unsigned char lds[32768];

    // XCD-chunked mapping: XCD x gets bh in [x*4, x*4+4) -> its L2 holds the
    // 4 A-panels (4 MB) shared by its 16-nt sibling blocks.
    const int bid = blockIdx.x;                // 0..511
    const int c   = bid >> 3;                  // 0..63
    const int bh  = (bid & 7) * 4 + (c >> 4);  // 0..31
    const int nt  = c & 15;                    // 0..15

    const float* Bg  = B + (size_t)bh * (128 * 2048) + nt * 128;
    const float* Ag0 = A + (size_t)bh * (2048 * 128);
    float*       Cg0 = C + (size_t)bh * (2048 * 2048) + nt * 128;

    const int t = threadIdx.x;

    // ---- stage B tile: 128(k) x 128(n) fp32, in-register 4x4 transpose
    //      -> bf16 LDS Bt[n][k], swizzled ----
#pragma unroll
    for (int s = 0; s < 4; ++s) {
        const int k0 = s * 32 + ((t >> 5) << 2);
        const int n0 = (t & 31) << 2;
        const float4 r0 = *(const float4*)(Bg + (size_t)(k0 + 0) * 2048 + n0);
        const float4 r1 = *(const float4*)(Bg + (size_t)(k0 + 1) * 2048 + n0);
        const float4 r2 = *(const float4*)(Bg + (size_t)(k0 + 2) * 2048 + n0);
        const float4 r3 = *(const float4*)(Bg + (size_t)(k0 + 3) * 2048 + n0);
        const float c0[4] = {r0.x, r0.y, r0.z, r0.w};
        const float c1[4] = {r1.x, r1.y, r1.z, r1.w};
        const float c2[4] = {r2.x, r2.y, r2.z, r2.w};
        const float c3[4] = {r3.x, r3.y, r3.z, r3.w};
#pragma unroll
        for (int j = 0; j < 4; ++j) {
            uint2 w;
            w.x = (unsigned int)f2bf(c0[j]) | ((unsigned int)f2bf(c1[j]) << 16);
            w.y = (unsigned int)f2bf(c2[j]) | ((unsigned int)f2bf(c3[j]) << 16);
            *(uint2*)(&lds[swz(n0 + j, k0)]) = w;
        }
    }

    __syncthreads();

    // ---- persistent mt-loop: wave w owns rows [w*32, w*32+32) of each tile.
    // 32x32x16 MFMA: A lane l holds A[ml][kh*8 + j]; B lane l holds
    // Bt[nbase+ml][kh*8 + j]; D reg r holds C[(r&3)+8*(r>>2)+4*kh][ml].
    const int l  = t & 63;
    const int w  = t >> 6;
    const int wm = w * 32;
    const int ml = l & 31;          // m-lane (A row) / n-lane (B col)
    const int kh = l >> 5;          // k-half (0/1)

    f32x4  raw[8][2];               // prefetched fp32 A row: 8 ksteps x 8 floats
    bf16x8 abf[8];                  // converted bf16 A fragments per kstep

    // prefetch tile 0: lane's whole A row (wm+ml), k = ks*16 + kh*8 + 0..7
    {
        const float* p = Ag0 + (size_t)(wm + ml) * 128 + kh * 8;
#pragma unroll
        for (int ks = 0; ks < 8; ++ks) {
            raw[ks][0] = *(const f32x4*)(p + ks * 16);
            raw[ks][1] = *(const f32x4*)(p + ks * 16 + 4);
        }
    }

#pragma unroll 1
    for (int mt = 0; mt < 16; ++mt) {
        // convert prefetched raw -> bf16 fragments (frees raw regs)
#pragma unroll
        for (int ks = 0; ks < 8; ++ks) {
            bf16x8 v;
#pragma unroll
            for (int j = 0; j < 4; ++j) {
                v[j]     = (short)f2bf(raw[ks][0][j]);
                v[4 + j] = (short)f2bf(raw[ks][1][j]);
            }
            abf[ks] = v;
        }

        // issue next tile's A loads BEFORE this tile's stores (older in the
        // vmcnt FIFO -> never wait behind the store drain)
        if (mt < 15) {
            const float* p = Ag0 + (size_t)((mt + 1) * 128 + wm + ml) * 128 + kh * 8;
#pragma unroll
            for (int ks = 0; ks < 8; ++ks) {
                raw[ks][0] = *(const f32x4*)(p + ks * 16);
                raw[ks][1] = *(const f32x4*)(p + ks * 16 + 4);
            }
        }

        f32x16 acc[4] = {};
#pragma unroll
        for (int ks = 0; ks < 8; ++ks) {
            const int kb = ks * 16 + kh * 8;
#pragma unroll
            for (int ni = 0; ni < 4; ++ni) {
                const bf16x8 b = *(const bf16x8*)(&lds[swz(ni * 32 + ml, kb)]);
                acc[ni] = __builtin_amdgcn_mfma_f32_32x32x16_bf16(
                    abf[ks], b, acc[ni], 0, 0, 0);
            }
        }

        // ---- full-line stores: reg r across a half-wave = 32 consecutive
        // floats of one C row = one complete 128B line. 2 lines per inst,
        // nontemporal (C never re-read, no RFO, no L2 pollution). ----
        float* Cr = Cg0 + (size_t)(mt * 128 + wm + 4 * kh) * 2048 + ml;
#pragma unroll
        for (int ni = 0; ni < 4; ++ni) {
#pragma unroll
            for (int r = 0; r < 16; ++r) {
                const int m = (r & 3) + 8 * (r >> 2);   // + 4*kh folded into Cr
                __builtin_nontemporal_store(
                    acc[ni][r], Cr + (size_t)m * 2048 + ni * 32);
            }
        }
    }
}

extern "C" void kernel_launch(void* const* d_in, const int* in_sizes, int n_in,
                              void* d_out, int out_size, void* d_ws, size_t ws_size,
                              hipStream_t stream) {
    const float* x1 = (const float*)d_in[0];  // (2,16,2048,128)
    const float* x2 = (const float*)d_in[1];  // (2,16,128,2048)
    float* out = (float*)d_out;               // (2,16,2048,2048)
    gemm_persist<<<dim3(512), dim3(256), 0, stream>>>(x1, x2, out);
}